// Round 12
// baseline (698.162 us; speedup 1.0000x reference)
//
#include <hip/hip_runtime.h>
#include <math.h>

// Differentiable A* forward (training mode), N=4096, Tmax=1024.
// R11 = R9 (best proven: 437 us search) + SAFE runner-up row speculation:
//  - winner(t+2) is provably either runner-up(t+1) or a fresh child of
//    ind(t+1). Hold the runner-up's row in registers, fetched at the TOP of
//    each step (full ~1 step of flight), consumed next step on hit -> the
//    per-step L2 row latency vanishes on hits.
//  - winner row load issues UNCONDITIONALLY before the hit branch (R7's
//    mistake: gating the load). No discovery touches (R8's mistake: VMEM
//    queue flood). M2 chain computed AFTER ind is resolved (off-path) and
//    is a pure hint: wrong M2 can only lower hit rate, never correctness.
// All state-update logic byte-identical to R9 (absmax 0.0): bit-packed
// monotone keys, one exact f64 wave-max argmax + first-index tiebreak,
// header-less padded CSR, {g,par} float2, register closedm, early-stop
// backtrack.

#define NN    4096
#define TMAXI 1024
#define CAP   96     // entries/row, padded (deg ~ 41 +/- 6.4; 96 = +8.7 sigma)
#define STR9  96     // float2 stride/row = 768 B

__device__ __forceinline__ float fexp_of(float g, float h, float open) {
    // f = 0.5*g + 0.5*h ; f_exp = exp(-f/64) * open   (1/64 exact)
    float f = __fadd_rn(__fmul_rn(0.5f, g), __fmul_rn(0.5f, h));
    return __fmul_rn(expf(__fmul_rn(-f, 0.015625f)), open);
}

template <int CTRL, int RMASK>
__device__ __forceinline__ double dpp_mov_d(double x) {
    int lo = __double2loint(x), hi = __double2hiint(x);
    lo = __builtin_amdgcn_update_dpp(lo, lo, CTRL, RMASK, 0xf, false);
    hi = __builtin_amdgcn_update_dpp(hi, hi, CTRL, RMASK, 0xf, false);
    return __hiloint2double(hi, lo);
}

// 64-lane f64 max (operands in {0} U [1,2), no NaN); proven R3/R6/R9.
__device__ __forceinline__ double wave_max_f64(double x) {
    x = fmax(x, dpp_mov_d<0x111, 0xf>(x));   // row_shr:1
    x = fmax(x, dpp_mov_d<0x112, 0xf>(x));   // row_shr:2
    x = fmax(x, dpp_mov_d<0x114, 0xf>(x));   // row_shr:4
    x = fmax(x, dpp_mov_d<0x118, 0xf>(x));   // row_shr:8
    x = fmax(x, dpp_mov_d<0x142, 0xa>(x));   // bcast15
    x = fmax(x, dpp_mov_d<0x143, 0xc>(x));   // bcast31
    int lo = __builtin_amdgcn_readlane(__double2loint(x), 63);
    int hi = __builtin_amdgcn_readlane(__double2hiint(x), 63);
    return __hiloint2double(hi, lo);
}

// ---------------- preprocessing: wadj -> padded CSR (no header) -------------
__global__ __launch_bounds__(256)
void build_csr9(const float* __restrict__ wadj, float2* __restrict__ ent)
{
    __shared__ int lcnt;
    const int r = blockIdx.x;
    if (threadIdx.x == 0) lcnt = 0;
    __syncthreads();
    const float4* wrow = (const float4*)(wadj + (size_t)r * NN);
    for (int c = 0; c < NN / (256 * 4); ++c) {
        int t4 = c * 256 + threadIdx.x;
        float4 w4 = wrow[t4];
        float wv[4] = {w4.x, w4.y, w4.z, w4.w};
        #pragma unroll
        for (int k = 0; k < 4; ++k) {
            int col = t4 * 4 + k;
            float w = wv[k];
            if (col != r && w != 0.0f && !isinf(w)) {
                int p = atomicAdd(&lcnt, 1);
                if (p < CAP)
                    ent[(size_t)r * STR9 + p] =
                        make_float2(__int_as_float(col), w);
            }
        }
    }
    __syncthreads();
    // pad remaining slots with col = r (self; always closed at expansion time)
    int base = min(lcnt, CAP);
    for (int p = base + (int)threadIdx.x; p < CAP; p += 256)
        ent[(size_t)r * STR9 + p] = make_float2(__int_as_float(r), 0.0f);
}

// ---------------- main search (1 block: wave0 search, wave1 L2 prefetch) ----
__global__ __launch_bounds__(128, 1)
void astar_fwd11(const int* __restrict__ start_p,
                 const int* __restrict__ goal_p,
                 const float* __restrict__ cost_maps,
                 const float* __restrict__ wadj,
                 const float2* __restrict__ ent,
                 float* __restrict__ scratch,
                 float* __restrict__ out)
{
    __shared__ __align__(16) unsigned long long ls_key[NN];  // 32 KB
    __shared__ __align__(16) float2 ls_gp[NN];               // 32 KB {g,par}
    __shared__ __align__(16) float ls_h[NN];                 // reused as pm
    __shared__ __align__(16) unsigned long long ls_bm[64];   // block max keys

    const int tid = threadIdx.x;

    if (tid >= 64) {
        // ---- prefetch wave: stream CSR into this XCD's L2, then exit ----
        const float4* p = (const float4*)ent;
        const int total = NN * (STR9 / 2);
        float acc = 0.0f;
        int l = tid - 64;
        #pragma unroll 4
        for (int i = l; i < total; i += 64) acc += p[i].x;
        scratch[l] = acc;                       // defeat DCE
        return;
    }

    const int lane  = tid;
    const int start = start_p[0];
    const int goal  = goal_p[0];

    // ---- init (identical to R9) ----
    {
        const float4* c4 = (const float4*)cost_maps;
        const float4* w4 = (const float4*)(wadj + (size_t)start * NN);
        const float gf = (float)goal;
        for (int c = 0; c < NN / (64 * 4); ++c) {
            int j4 = c * 64 + lane;
            float4 hv4 = c4[j4];
            float4 gv4 = w4[j4];
            if (start >= j4 * 4 && start < j4 * 4 + 4)
                ((float*)&gv4)[start - j4 * 4] = 0.0f;   // diag zeroed
            ((float4*)ls_h)[j4] = hv4;
            float gv[4] = {gv4.x, gv4.y, gv4.z, gv4.w};
            #pragma unroll
            for (int k = 0; k < 4; ++k)
                ls_gp[j4 * 4 + k] = make_float2(gv[k], gf);
        }
        for (int c = 0; c < (int)(NN * sizeof(unsigned long long) /
                                  (64 * sizeof(float4))); ++c)
            ((float4*)ls_key)[c * 64 + lane] = make_float4(0.f, 0.f, 0.f, 0.f);
        ls_bm[lane] = 0ull;
        if (lane == 0) {
            float fe = fexp_of(0.0f, ls_h[start], 1.0f);  // g0[start]=0, open=1
            unsigned long long kb = 0x3FF0000000000000ull
                | ((unsigned long long)__float_as_uint(fe) << 12)
                | (unsigned)(4095 - start);
            ls_key[start] = kb;
            ls_bm[start >> 6] = kb;
        }
    }

    int ind  = start;           // step 0 expands start (only open node)
    int cand = -1;              // runner-up to prefetch this step
    int spec_id = -1;           // id whose row is held in s_e0/s_e1
    float2 s_e0 = make_float2(0.f, 0.f);
    float2 s_e1 = make_float2(0.f, 0.f);
    unsigned long long closedm = 0ull;
    int tf = 0;

    for (int t = 0; t < TMAXI; ++t) {
        const int b = ind >> 6;

        // ---- winner row: ALWAYS issue (before hit branch; free on hit) ----
        const float2* row = ent + (size_t)ind * STR9;
        float2 t0 = row[lane];
        float2 t1 = make_float2(0.0f, 0.0f);
        if (lane < 32) t1 = row[64 + lane];

        // ---- spec fetch for NEXT step's candidate (full step of flight) ----
        float2 n0 = make_float2(0.0f, 0.0f), n1 = make_float2(0.0f, 0.0f);
        if (cand >= 0) {
            const float2* rw = ent + (size_t)cand * STR9;
            n0 = rw[lane];
            if (lane < 32) n1 = rw[64 + lane];
        }

        // ---- DS reads up front (identical to R9) ----
        double bm_v = __longlong_as_double((long long)ls_bm[lane]);
        double kb_v = __longlong_as_double(
                          (long long)ls_key[(b << 6) + lane]);
        float  gind = ls_gp[ind].x;

        // ---- consume held row on hit (no wait on t0/t1), else wait t ----
        float2 e0, e1;
        if (ind == spec_id) { e0 = s_e0; e1 = s_e1; }
        else                { e0 = t0;   e1 = t1;   }
        s_e0 = n0; s_e1 = n1; spec_id = cand;    // rotate holding regs

        // ---- K_b: block-b max excluding ind (overlaps row VMEM) ----
        double kx = kb_v;
        if (lane == (ind & 63)) kx = 0.0;
        if (kx <= 1.0) kx = 0.0;
        double K_b = wave_max_f64(kx);

        // ---- close ind (plain writes BEFORE child gathers; DS in-order) ----
        if (lane == 0) {
            ls_key[ind] = 0x3FF0000000000000ull;   // sentinel 1.0 (closed)
            ls_bm[b] = (unsigned long long)__double_as_longlong(K_b);
        }
        if (lane == b) closedm |= (1ull << (ind & 63));

        const float indf = (float)ind;
        double nk0 = 0.0, nk1 = 0.0;

        // ---- open fresh neighbors (key==0): g=fl(gind+w), par=ind ----
        {
            int j = __float_as_int(e0.x);
            unsigned long long kj = ls_key[j];
            float hj = ls_h[j];
            if (kj == 0ull) {                   // untouched (pads: j==ind closed)
                float g2 = __fadd_rn(gind, e0.y);
                float fe = fexp_of(g2, hj, 1.0f);
                unsigned long long kb = 0x3FF0000000000000ull
                    | ((unsigned long long)__float_as_uint(fe) << 12)
                    | (unsigned)(4095 - j);
                ls_gp[j]  = make_float2(g2, indf);
                ls_key[j] = kb;
                atomicMax(&ls_bm[j >> 6], kb);
                nk0 = __longlong_as_double((long long)kb);
            }
        }
        if (lane < 32) {
            int j = __float_as_int(e1.x);
            unsigned long long kj = ls_key[j];
            float hj = ls_h[j];
            if (kj == 0ull) {
                float g2 = __fadd_rn(gind, e1.y);
                float fe = fexp_of(g2, hj, 1.0f);
                unsigned long long kb = 0x3FF0000000000000ull
                    | ((unsigned long long)__float_as_uint(fe) << 12)
                    | (unsigned)(4095 - j);
                ls_gp[j]  = make_float2(g2, indf);
                ls_key[j] = kb;
                atomicMax(&ls_bm[j >> 6], kb);
                nk1 = __longlong_as_double((long long)kb);
            }
        }

        tf = t;
        if (ind == goal) break;             // snm==1.0 >= 1e-8 always

        // ---- per-lane top-2, then winner chain (critical) ----
        double bmx = (lane == b) ? 0.0 : bm_v;
        double a0 = fmax(bmx, kx), b0 = fmin(bmx, kx);
        double a1 = fmax(nk0, nk1), b1 = fmin(nk0, nk1);
        double l1 = fmax(a0, a1);
        double l2 = fmax(fmin(a0, a1), fmax(b0, b1));

        double M1 = wave_max_f64(l1);
        int ind_next;
        if (M1 > 1.0) {
            unsigned long long mb = (unsigned long long)__double_as_longlong(M1);
            ind_next = 4095 - (int)(mb & 0xFFFu);
        } else {
            ind_next = 0;                   // no open nodes: argmax(0s) = 0
        }
        ind = __builtin_amdgcn_readfirstlane(ind_next);

        // ---- runner-up chain (hint only; off the ind critical path) ----
        double c2 = (l1 == M1) ? l2 : l1;   // unique keys: one lane masked
        double M2 = wave_max_f64(c2);
        int cn;
        if (M2 > 1.0) {
            unsigned long long mb2 = (unsigned long long)__double_as_longlong(M2);
            cn = 4095 - (int)(mb2 & 0xFFFu);
        } else {
            cn = -1;
        }
        cand = __builtin_amdgcn_readfirstlane(cn);
    }

    // ---- outputs: hist from closed masks; path marks with early-stop ----
    ls_bm[lane] = closedm;                  // exchange masks via LDS
    for (int c = 0; c < NN / (64 * 4); ++c) // reuse ls_h as path-mark array
        ((float4*)ls_h)[c * 64 + lane] = make_float4(0.f, 0.f, 0.f, 0.f);
    if (lane == 0) {
        ls_h[goal] = 1.0f;
        int loc = (int)ls_gp[goal].y;
        for (int i = 0; i < tf; ++i) {
            if (ls_h[loc] != 0.0f) break;   // walk repeats: no new marks
            ls_h[loc] = 1.0f;
            loc = (int)ls_gp[loc].y;
        }
    }
    for (int c = 0; c < NN / (64 * 4); ++c) {
        int j4 = c * 64 + lane;
        unsigned long long m = ls_bm[j4 >> 4];
        unsigned int bits = (unsigned int)(m >> ((j4 & 15) * 4)) & 0xFu;
        float4 hist4;
        hist4.x = (bits & 1u) ? 1.0f : 0.0f;
        hist4.y = (bits & 2u) ? 1.0f : 0.0f;
        hist4.z = (bits & 4u) ? 1.0f : 0.0f;
        hist4.w = (bits & 8u) ? 1.0f : 0.0f;
        ((float4*)out)[j4]        = hist4;
        ((float4*)(out + NN))[j4] = ((const float4*)ls_h)[j4];
    }
}

// ---------------- R0 dense fallback (no workspace needed) -------------------
__device__ __forceinline__ float clip01(float x) {
    return fminf(fmaxf(x, 0.0f), 1.0f);
}

__global__ __launch_bounds__(1024, 1)
void astar_fwd(const int* __restrict__ start_p,
               const int* __restrict__ goal_p,
               const float* __restrict__ cost_maps,
               const float* __restrict__ adj,
               const float* __restrict__ wadj,
               float* __restrict__ out)
{
    __shared__ __align__(16) float ls_open[NN];
    __shared__ __align__(16) float ls_hist[NN];
    __shared__ __align__(16) float ls_g[NN];
    __shared__ __align__(16) float ls_par[NN];
    __shared__ __align__(16) float ls_fe[NN];
    __shared__ __align__(16) float ls_h[NN];
    __shared__ float red_v[16];
    __shared__ float red_s[16];
    __shared__ int   red_i[16];
    __shared__ float bc_snm, bc_gind;
    __shared__ int   bc_ind, ls_done, ls_tf;

    const int tid   = threadIdx.x;
    const int start = start_p[0];
    const int goal  = goal_p[0];

    for (int k = 0; k < 4; ++k) {
        int j = tid * 4 + k;
        float hv = cost_maps[j];
        float gv = wadj[(size_t)start * NN + j];
        if (j == start) gv = 0.0f;
        float ov = (j == start) ? 1.0f : 0.0f;
        ls_h[j] = hv; ls_g[j] = gv; ls_open[j] = ov;
        ls_hist[j] = 0.0f; ls_par[j] = (float)goal;
        ls_fe[j] = fexp_of(gv, hv, ov);
    }
    if (tid == 0) { ls_done = 0; ls_tf = 0; }
    __syncthreads();

    for (int t = 0; t < TMAXI; ++t) {
        float4 fe4 = *(const float4*)&ls_fe[tid * 4];
        float v0 = fe4.x, v1 = fe4.y, v2 = fe4.z, v3 = fe4.w;
        float sum = ((v0 + v1) + v2) + v3;
        float best = v0; int bi = tid * 4;
        if (v1 > best) { best = v1; bi = tid * 4 + 1; }
        if (v2 > best) { best = v2; bi = tid * 4 + 2; }
        if (v3 > best) { best = v3; bi = tid * 4 + 3; }
        #pragma unroll
        for (int off = 32; off > 0; off >>= 1) {
            float ov = __shfl_down(best, off);
            int   oi = __shfl_down(bi, off);
            float os = __shfl_down(sum, off);
            sum += os;
            if (ov > best || (ov == best && oi < bi)) { best = ov; bi = oi; }
        }
        if ((tid & 63) == 0) {
            int w = tid >> 6;
            red_v[w] = best; red_s[w] = sum; red_i[w] = bi;
        }
        __syncthreads();
        if (tid == 0) {
            float denom = red_s[0]; best = red_v[0]; bi = red_i[0];
            #pragma unroll
            for (int w = 1; w < 16; ++w) {
                denom += red_s[w];
                if (red_v[w] > best || (red_v[w] == best && red_i[w] < bi)) {
                    best = red_v[w]; bi = red_i[w];
                }
            }
            int ind = bi;
            float dg = (denom == 0.0f) ? 1.0f : denom;
            float y_ind = ls_fe[ind] / dg;
            float snm = __fadd_rn(__fsub_rn(1.0f, y_ind), y_ind);
            ls_open[ind] = clip01(__fsub_rn(ls_open[ind], snm));
            ls_hist[ind] = clip01(__fadd_rn(ls_hist[ind], snm));
            ls_fe[ind]   = fexp_of(ls_g[ind], ls_h[ind], ls_open[ind]);
            bc_ind = ind; bc_snm = snm; bc_gind = ls_g[ind];
            ls_tf = t;
            if (ind == goal && snm >= 1e-8f) ls_done = 1;
        }
        __syncthreads();
        {
            const int   ind  = bc_ind;
            const float snm  = bc_snm;
            const float gind = bc_gind;
            const float indf = (float)ind;
            float4 a4 = ((const float4*)(adj  + (size_t)ind * NN))[tid];
            float4 w4 = ((const float4*)(wadj + (size_t)ind * NN))[tid];
            float av[4] = {a4.x, a4.y, a4.z, a4.w};
            float wvv[4] = {w4.x, w4.y, w4.z, w4.w};
            #pragma unroll
            for (int k = 0; k < 4; ++k) {
                int j = tid * 4 + k;
                float a = av[k], w = wvv[k];
                if (j == ind) { a = 0.0f; w = 0.0f; }
                if (a != 0.0f) {
                    float o = ls_open[j], hi = ls_hist[j], gj = ls_g[j];
                    float one_o = __fsub_rn(1.0f, o);
                    float one_h = __fsub_rn(1.0f, hi);
                    float sm    = __fmul_rn(snm, a);
                    float neigh = __fmul_rn(__fmul_rn(sm, one_o), one_h);
                    float g2    = __fadd_rn(gind, w);
                    float cmp   = (gj > g2) ? 1.0f : 0.0f;
                    float s   = __fadd_rn(__fmul_rn(one_o, one_h),
                                          __fmul_rn(o, cmp));
                    float idx = __fmul_rn(s, neigh);
                    if (idx != 0.0f) {
                        float omi = __fsub_rn(1.0f, idx);
                        float gn = __fadd_rn(__fmul_rn(g2, idx),
                                             __fmul_rn(gj, omi));
                        float on = clip01(__fadd_rn(o, idx));
                        float pn = __fadd_rn(__fmul_rn(indf, idx),
                                             __fmul_rn(ls_par[j], omi));
                        ls_g[j] = gn; ls_open[j] = on; ls_par[j] = pn;
                        ls_fe[j] = fexp_of(gn, ls_h[j], on);
                    }
                }
            }
        }
        __syncthreads();
        if (ls_done) break;
    }

    for (int k = 0; k < 4; ++k) {
        int j = tid * 4 + k;
        out[j] = ls_hist[j];
        out[NN + j] = (j == goal) ? 1.0f : 0.0f;
    }
    __syncthreads();
    if (tid == 0) {
        int tfv = ls_tf;
        int loc = (int)ls_par[goal];
        for (int i = 0; i < tfv; ++i) {
            out[NN + loc] = 1.0f;
            loc = (int)ls_par[loc];
        }
    }
}

extern "C" void kernel_launch(void* const* d_in, const int* in_sizes, int n_in,
                              void* d_out, int out_size, void* d_ws, size_t ws_size,
                              hipStream_t stream)
{
    const int*   start_p = (const int*)d_in[0];
    const int*   goal_p  = (const int*)d_in[1];
    const float* cost    = (const float*)d_in[2];
    // d_in[3] = nodes (coords) — unused
    const float* adj     = (const float*)d_in[4];
    const float* wadj    = (const float*)d_in[5];
    float* out = (float*)d_out;

    const size_t csr_bytes = (size_t)NN * STR9 * sizeof(float2);  // 3.0 MB
    const size_t need = csr_bytes + 64 * sizeof(float);
    if (ws_size >= need) {
        float2* ent     = (float2*)d_ws;
        float*  scratch = (float*)((char*)d_ws + csr_bytes);
        build_csr9<<<dim3(NN), dim3(256), 0, stream>>>(wadj, ent);
        astar_fwd11<<<dim3(1), dim3(128), 0, stream>>>(start_p, goal_p, cost,
                                                       wadj, ent, scratch, out);
    } else {
        astar_fwd<<<dim3(1), dim3(1024), 0, stream>>>(start_p, goal_p, cost,
                                                      adj, wadj, out);
    }
}

// Round 13
// 556.094 us; speedup vs baseline: 1.2555x; 1.2555x over previous
//
#include <hip/hip_runtime.h>
#include <math.h>

// Differentiable A* forward (training mode), N=4096, Tmax=1024.
// R12 = revert to R9 exactly (proven best: 437 us search / 557 us total).
// Post-mortem of R7/R8/R10/R11: the per-step CSR row load is already fully
// hidden behind the DS reads + K_b wave-max the hardware overlaps with it;
// every speculation/prefetch/layout variant only ADDED serial VALU to the
// loop-carried chain and regressed. R9's structure is the empirical minimum:
//  - bit-packed monotone keys: K = 0x3FF0...0 | (fe_bits<<12) | (4095-j);
//    positive-double ordering == u64 bit ordering -> argmax + exact global
//    first-index tiebreak in ONE f64 DPP wave-max; encode/decode = int ops.
//  - header-less CSR rows padded to CAP with col=r (inert: r is open/closed,
//    never fresh, at its own expansion).
//  - incremental frontier: 64 block-max keys in LDS; per-step patch of the
//    expanded block (K_b) + fresh-child keys folded in registers.
//  - {g, par} packed float2; hist = per-lane closed bitmask registers;
//    backtrack with early-stop (walk cycles add no new marks).
// State-update chains bit-identical to R0 (absmax 0.0 across R1-R11):
// g=fl(gind+w), fe = exp(fl(-fl(0.5g+0.5h)*2^-6)) chain, par=ind exact,
// snm==1.0 proven exact (Sterbenz + rounding argument, R3).

#define NN    4096
#define TMAXI 1024
#define CAP   96     // entries/row, padded (deg ~ 41 +/- 6.4; 96 = +8.7 sigma)
#define STR9  96     // float2 stride/row = 768 B

__device__ __forceinline__ float fexp_of(float g, float h, float open) {
    // f = 0.5*g + 0.5*h ; f_exp = exp(-f/64) * open   (1/64 exact)
    float f = __fadd_rn(__fmul_rn(0.5f, g), __fmul_rn(0.5f, h));
    return __fmul_rn(expf(__fmul_rn(-f, 0.015625f)), open);
}

template <int CTRL, int RMASK>
__device__ __forceinline__ double dpp_mov_d(double x) {
    int lo = __double2loint(x), hi = __double2hiint(x);
    lo = __builtin_amdgcn_update_dpp(lo, lo, CTRL, RMASK, 0xf, false);
    hi = __builtin_amdgcn_update_dpp(hi, hi, CTRL, RMASK, 0xf, false);
    return __hiloint2double(hi, lo);
}

// 64-lane f64 max (operands in {0} U [1,2), no NaN); proven R3/R6/R9.
__device__ __forceinline__ double wave_max_f64(double x) {
    x = fmax(x, dpp_mov_d<0x111, 0xf>(x));   // row_shr:1
    x = fmax(x, dpp_mov_d<0x112, 0xf>(x));   // row_shr:2
    x = fmax(x, dpp_mov_d<0x114, 0xf>(x));   // row_shr:4
    x = fmax(x, dpp_mov_d<0x118, 0xf>(x));   // row_shr:8
    x = fmax(x, dpp_mov_d<0x142, 0xa>(x));   // bcast15
    x = fmax(x, dpp_mov_d<0x143, 0xc>(x));   // bcast31
    int lo = __builtin_amdgcn_readlane(__double2loint(x), 63);
    int hi = __builtin_amdgcn_readlane(__double2hiint(x), 63);
    return __hiloint2double(hi, lo);
}

// ---------------- preprocessing: wadj -> padded CSR (no header) -------------
__global__ __launch_bounds__(256)
void build_csr9(const float* __restrict__ wadj, float2* __restrict__ ent)
{
    __shared__ int lcnt;
    const int r = blockIdx.x;
    if (threadIdx.x == 0) lcnt = 0;
    __syncthreads();
    const float4* wrow = (const float4*)(wadj + (size_t)r * NN);
    for (int c = 0; c < NN / (256 * 4); ++c) {
        int t4 = c * 256 + threadIdx.x;
        float4 w4 = wrow[t4];
        float wv[4] = {w4.x, w4.y, w4.z, w4.w};
        #pragma unroll
        for (int k = 0; k < 4; ++k) {
            int col = t4 * 4 + k;
            float w = wv[k];
            if (col != r && w != 0.0f && !isinf(w)) {
                int p = atomicAdd(&lcnt, 1);
                if (p < CAP)
                    ent[(size_t)r * STR9 + p] =
                        make_float2(__int_as_float(col), w);
            }
        }
    }
    __syncthreads();
    // pad remaining slots with col = r (self; never fresh at expansion time)
    int base = min(lcnt, CAP);
    for (int p = base + (int)threadIdx.x; p < CAP; p += 256)
        ent[(size_t)r * STR9 + p] = make_float2(__int_as_float(r), 0.0f);
}

// ---------------- main search (1 block: wave0 search, wave1 L2 prefetch) ----
__global__ __launch_bounds__(128, 1)
void astar_fwd9(const int* __restrict__ start_p,
                const int* __restrict__ goal_p,
                const float* __restrict__ cost_maps,
                const float* __restrict__ wadj,
                const float2* __restrict__ ent,
                float* __restrict__ scratch,
                float* __restrict__ out)
{
    __shared__ __align__(16) unsigned long long ls_key[NN];  // 32 KB
    __shared__ __align__(16) float2 ls_gp[NN];               // 32 KB {g,par}
    __shared__ __align__(16) float ls_h[NN];                 // reused as pm
    __shared__ __align__(16) unsigned long long ls_bm[64];   // block max keys

    const int tid = threadIdx.x;

    if (tid >= 64) {
        // ---- prefetch wave: stream CSR into this XCD's L2, then exit ----
        const float4* p = (const float4*)ent;
        const int total = NN * (STR9 / 2);
        float acc = 0.0f;
        int l = tid - 64;
        #pragma unroll 4
        for (int i = l; i < total; i += 64) acc += p[i].x;
        scratch[l] = acc;                       // defeat DCE
        return;
    }

    const int lane  = tid;
    const int start = start_p[0];
    const int goal  = goal_p[0];

    // ---- init ----
    {
        const float4* c4 = (const float4*)cost_maps;
        const float4* w4 = (const float4*)(wadj + (size_t)start * NN);
        const float gf = (float)goal;
        for (int c = 0; c < NN / (64 * 4); ++c) {
            int j4 = c * 64 + lane;
            float4 hv4 = c4[j4];
            float4 gv4 = w4[j4];
            if (start >= j4 * 4 && start < j4 * 4 + 4)
                ((float*)&gv4)[start - j4 * 4] = 0.0f;   // diag zeroed
            ((float4*)ls_h)[j4] = hv4;
            float gv[4] = {gv4.x, gv4.y, gv4.z, gv4.w};
            #pragma unroll
            for (int k = 0; k < 4; ++k)
                ls_gp[j4 * 4 + k] = make_float2(gv[k], gf);
        }
        for (int c = 0; c < (int)(NN * sizeof(unsigned long long) /
                                  (64 * sizeof(float4))); ++c)
            ((float4*)ls_key)[c * 64 + lane] = make_float4(0.f, 0.f, 0.f, 0.f);
        ls_bm[lane] = 0ull;
        if (lane == 0) {
            float fe = fexp_of(0.0f, ls_h[start], 1.0f);  // g0[start]=0, open=1
            unsigned long long kb = 0x3FF0000000000000ull
                | ((unsigned long long)__float_as_uint(fe) << 12)
                | (unsigned)(4095 - start);
            ls_key[start] = kb;
            ls_bm[start >> 6] = kb;
        }
    }

    int ind = start;            // step 0 expands start (only open node)
    unsigned long long closedm = 0ull;
    int tf = 0;

    for (int t = 0; t < TMAXI; ++t) {
        const int b = ind >> 6;

        // ---- issue all latency ops up front (row VMEM + three DS reads) ----
        const float2* row = ent + (size_t)ind * STR9;
        float2 e0 = row[lane];
        float2 e1 = make_float2(0.0f, 0.0f);
        if (lane < 32) e1 = row[64 + lane];
        double bm_v = __longlong_as_double((long long)ls_bm[lane]);
        double kb_v = __longlong_as_double(
                          (long long)ls_key[(b << 6) + lane]);
        float  gind = ls_gp[ind].x;

        // ---- K_b: block-b max excluding ind (overlaps row VMEM) ----
        double kx = kb_v;
        if (lane == (ind & 63)) kx = 0.0;
        if (kx <= 1.0) kx = 0.0;
        double K_b = wave_max_f64(kx);

        // ---- close ind (plain writes BEFORE child atomics; DS in-order) ----
        if (lane == 0) {
            ls_key[ind] = 0x3FF0000000000000ull;   // sentinel 1.0 (closed)
            ls_bm[b] = (unsigned long long)__double_as_longlong(K_b);
        }
        if (lane == b) closedm |= (1ull << (ind & 63));

        const float indf = (float)ind;
        double nk0 = 0.0, nk1 = 0.0;

        // ---- open fresh neighbors (key==0): g=fl(gind+w), par=ind ----
        {
            int j = __float_as_int(e0.x);
            unsigned long long kj = ls_key[j];
            float hj = ls_h[j];
            if (kj == 0ull) {                  // untouched (pads: j==ind open/closed)
                float g2 = __fadd_rn(gind, e0.y);
                float fe = fexp_of(g2, hj, 1.0f);
                unsigned long long kb = 0x3FF0000000000000ull
                    | ((unsigned long long)__float_as_uint(fe) << 12)
                    | (unsigned)(4095 - j);
                ls_gp[j]  = make_float2(g2, indf);
                ls_key[j] = kb;
                atomicMax(&ls_bm[j >> 6], kb);
                nk0 = __longlong_as_double((long long)kb);
            }
        }
        if (lane < 32) {
            int j = __float_as_int(e1.x);
            unsigned long long kj = ls_key[j];
            float hj = ls_h[j];
            if (kj == 0ull) {
                float g2 = __fadd_rn(gind, e1.y);
                float fe = fexp_of(g2, hj, 1.0f);
                unsigned long long kb = 0x3FF0000000000000ull
                    | ((unsigned long long)__float_as_uint(fe) << 12)
                    | (unsigned)(4095 - j);
                ls_gp[j]  = make_float2(g2, indf);
                ls_key[j] = kb;
                atomicMax(&ls_bm[j >> 6], kb);
                nk1 = __longlong_as_double((long long)kb);
            }
        }

        tf = t;
        if (ind == goal) break;             // snm==1.0 >= 1e-8 always

        // ---- fused winner reduction over {bmx, kx, nk0, nk1} ----
        double bmx = (lane == b) ? 0.0 : bm_v;
        double loc = fmax(fmax(bmx, kx), fmax(nk0, nk1));
        double M1 = wave_max_f64(loc);      // critical path
        int ind_next;
        if (M1 > 1.0) {
            unsigned long long mb = (unsigned long long)__double_as_longlong(M1);
            ind_next = 4095 - (int)(mb & 0xFFFu);
        } else {
            ind_next = 0;                   // no open nodes: argmax(0s) = 0
        }
        ind = __builtin_amdgcn_readfirstlane(ind_next);
    }

    // ---- outputs: hist from closed masks; path marks with early-stop ----
    ls_bm[lane] = closedm;                  // exchange masks via LDS
    for (int c = 0; c < NN / (64 * 4); ++c) // reuse ls_h as path-mark array
        ((float4*)ls_h)[c * 64 + lane] = make_float4(0.f, 0.f, 0.f, 0.f);
    if (lane == 0) {
        ls_h[goal] = 1.0f;
        int loc = (int)ls_gp[goal].y;
        for (int i = 0; i < tf; ++i) {
            if (ls_h[loc] != 0.0f) break;   // walk repeats: no new marks
            ls_h[loc] = 1.0f;
            loc = (int)ls_gp[loc].y;
        }
    }
    for (int c = 0; c < NN / (64 * 4); ++c) {
        int j4 = c * 64 + lane;
        unsigned long long m = ls_bm[j4 >> 4];
        unsigned int bits = (unsigned int)(m >> ((j4 & 15) * 4)) & 0xFu;
        float4 hist4;
        hist4.x = (bits & 1u) ? 1.0f : 0.0f;
        hist4.y = (bits & 2u) ? 1.0f : 0.0f;
        hist4.z = (bits & 4u) ? 1.0f : 0.0f;
        hist4.w = (bits & 8u) ? 1.0f : 0.0f;
        ((float4*)out)[j4]        = hist4;
        ((float4*)(out + NN))[j4] = ((const float4*)ls_h)[j4];
    }
}

// ---------------- R0 dense fallback (no workspace needed) -------------------
__device__ __forceinline__ float clip01(float x) {
    return fminf(fmaxf(x, 0.0f), 1.0f);
}

__global__ __launch_bounds__(1024, 1)
void astar_fwd(const int* __restrict__ start_p,
               const int* __restrict__ goal_p,
               const float* __restrict__ cost_maps,
               const float* __restrict__ adj,
               const float* __restrict__ wadj,
               float* __restrict__ out)
{
    __shared__ __align__(16) float ls_open[NN];
    __shared__ __align__(16) float ls_hist[NN];
    __shared__ __align__(16) float ls_g[NN];
    __shared__ __align__(16) float ls_par[NN];
    __shared__ __align__(16) float ls_fe[NN];
    __shared__ __align__(16) float ls_h[NN];
    __shared__ float red_v[16];
    __shared__ float red_s[16];
    __shared__ int   red_i[16];
    __shared__ float bc_snm, bc_gind;
    __shared__ int   bc_ind, ls_done, ls_tf;

    const int tid   = threadIdx.x;
    const int start = start_p[0];
    const int goal  = goal_p[0];

    for (int k = 0; k < 4; ++k) {
        int j = tid * 4 + k;
        float hv = cost_maps[j];
        float gv = wadj[(size_t)start * NN + j];
        if (j == start) gv = 0.0f;
        float ov = (j == start) ? 1.0f : 0.0f;
        ls_h[j] = hv; ls_g[j] = gv; ls_open[j] = ov;
        ls_hist[j] = 0.0f; ls_par[j] = (float)goal;
        ls_fe[j] = fexp_of(gv, hv, ov);
    }
    if (tid == 0) { ls_done = 0; ls_tf = 0; }
    __syncthreads();

    for (int t = 0; t < TMAXI; ++t) {
        float4 fe4 = *(const float4*)&ls_fe[tid * 4];
        float v0 = fe4.x, v1 = fe4.y, v2 = fe4.z, v3 = fe4.w;
        float sum = ((v0 + v1) + v2) + v3;
        float best = v0; int bi = tid * 4;
        if (v1 > best) { best = v1; bi = tid * 4 + 1; }
        if (v2 > best) { best = v2; bi = tid * 4 + 2; }
        if (v3 > best) { best = v3; bi = tid * 4 + 3; }
        #pragma unroll
        for (int off = 32; off > 0; off >>= 1) {
            float ov = __shfl_down(best, off);
            int   oi = __shfl_down(bi, off);
            float os = __shfl_down(sum, off);
            sum += os;
            if (ov > best || (ov == best && oi < bi)) { best = ov; bi = oi; }
        }
        if ((tid & 63) == 0) {
            int w = tid >> 6;
            red_v[w] = best; red_s[w] = sum; red_i[w] = bi;
        }
        __syncthreads();
        if (tid == 0) {
            float denom = red_s[0]; best = red_v[0]; bi = red_i[0];
            #pragma unroll
            for (int w = 1; w < 16; ++w) {
                denom += red_s[w];
                if (red_v[w] > best || (red_v[w] == best && red_i[w] < bi)) {
                    best = red_v[w]; bi = red_i[w];
                }
            }
            int ind = bi;
            float dg = (denom == 0.0f) ? 1.0f : denom;
            float y_ind = ls_fe[ind] / dg;
            float snm = __fadd_rn(__fsub_rn(1.0f, y_ind), y_ind);
            ls_open[ind] = clip01(__fsub_rn(ls_open[ind], snm));
            ls_hist[ind] = clip01(__fadd_rn(ls_hist[ind], snm));
            ls_fe[ind]   = fexp_of(ls_g[ind], ls_h[ind], ls_open[ind]);
            bc_ind = ind; bc_snm = snm; bc_gind = ls_g[ind];
            ls_tf = t;
            if (ind == goal && snm >= 1e-8f) ls_done = 1;
        }
        __syncthreads();
        {
            const int   ind  = bc_ind;
            const float snm  = bc_snm;
            const float gind = bc_gind;
            const float indf = (float)ind;
            float4 a4 = ((const float4*)(adj  + (size_t)ind * NN))[tid];
            float4 w4 = ((const float4*)(wadj + (size_t)ind * NN))[tid];
            float av[4] = {a4.x, a4.y, a4.z, a4.w};
            float wvv[4] = {w4.x, w4.y, w4.z, w4.w};
            #pragma unroll
            for (int k = 0; k < 4; ++k) {
                int j = tid * 4 + k;
                float a = av[k], w = wvv[k];
                if (j == ind) { a = 0.0f; w = 0.0f; }
                if (a != 0.0f) {
                    float o = ls_open[j], hi = ls_hist[j], gj = ls_g[j];
                    float one_o = __fsub_rn(1.0f, o);
                    float one_h = __fsub_rn(1.0f, hi);
                    float sm    = __fmul_rn(snm, a);
                    float neigh = __fmul_rn(__fmul_rn(sm, one_o), one_h);
                    float g2    = __fadd_rn(gind, w);
                    float cmp   = (gj > g2) ? 1.0f : 0.0f;
                    float s   = __fadd_rn(__fmul_rn(one_o, one_h),
                                          __fmul_rn(o, cmp));
                    float idx = __fmul_rn(s, neigh);
                    if (idx != 0.0f) {
                        float omi = __fsub_rn(1.0f, idx);
                        float gn = __fadd_rn(__fmul_rn(g2, idx),
                                             __fmul_rn(gj, omi));
                        float on = clip01(__fadd_rn(o, idx));
                        float pn = __fadd_rn(__fmul_rn(indf, idx),
                                             __fmul_rn(ls_par[j], omi));
                        ls_g[j] = gn; ls_open[j] = on; ls_par[j] = pn;
                        ls_fe[j] = fexp_of(gn, ls_h[j], on);
                    }
                }
            }
        }
        __syncthreads();
        if (ls_done) break;
    }

    for (int k = 0; k < 4; ++k) {
        int j = tid * 4 + k;
        out[j] = ls_hist[j];
        out[NN + j] = (j == goal) ? 1.0f : 0.0f;
    }
    __syncthreads();
    if (tid == 0) {
        int tfv = ls_tf;
        int loc = (int)ls_par[goal];
        for (int i = 0; i < tfv; ++i) {
            out[NN + loc] = 1.0f;
            loc = (int)ls_par[loc];
        }
    }
}

extern "C" void kernel_launch(void* const* d_in, const int* in_sizes, int n_in,
                              void* d_out, int out_size, void* d_ws, size_t ws_size,
                              hipStream_t stream)
{
    const int*   start_p = (const int*)d_in[0];
    const int*   goal_p  = (const int*)d_in[1];
    const float* cost    = (const float*)d_in[2];
    // d_in[3] = nodes (coords) — unused
    const float* adj     = (const float*)d_in[4];
    const float* wadj    = (const float*)d_in[5];
    float* out = (float*)d_out;

    const size_t csr_bytes = (size_t)NN * STR9 * sizeof(float2);  // 3.0 MB
    const size_t need = csr_bytes + 64 * sizeof(float);
    if (ws_size >= need) {
        float2* ent     = (float2*)d_ws;
        float*  scratch = (float*)((char*)d_ws + csr_bytes);
        build_csr9<<<dim3(NN), dim3(256), 0, stream>>>(wadj, ent);
        astar_fwd9<<<dim3(1), dim3(128), 0, stream>>>(start_p, goal_p, cost,
                                                      wadj, ent, scratch, out);
    } else {
        astar_fwd<<<dim3(1), dim3(1024), 0, stream>>>(start_p, goal_p, cost,
                                                      adj, wadj, out);
    }
}